// Round 1
// baseline (4858.490 us; speedup 1.0000x reference)
//
#include <hip/hip_runtime.h>
#include <math.h>

namespace {

constexpr int Bn = 8192;
constexpr int Dn = 508;
constexpr int Hn = 256;
constexpr int NSTEPS = 8;

constexpr int BM = 64;
constexpr int BN = 64;
constexpr int BK = 16;
constexpr int TP = BN + 4;  // padded LDS stride (68 floats = 272B, 16B-aligned rows)

__device__ __forceinline__ void mm_tile(const float (*As)[TP], const float (*Bs)[TP],
                                        int ty, int tx, float acc[4][4]) {
#pragma unroll
  for (int kk = 0; kk < BK; ++kk) {
    const float4 av = *(const float4*)(&As[kk][ty * 4]);
    const float4 bv = *(const float4*)(&Bs[kk][tx * 4]);
    const float a[4] = {av.x, av.y, av.z, av.w};
    const float b[4] = {bv.x, bv.y, bv.z, bv.w};
#pragma unroll
    for (int i = 0; i < 4; ++i)
#pragma unroll
      for (int j = 0; j < 4; ++j) acc[i][j] += a[i] * b[j];
  }
}

// y := x ; ld := 0
__global__ __launch_bounds__(256) void k_init(const float* __restrict__ x,
                                              float* __restrict__ y,
                                              float* __restrict__ ld) {
  const size_t n4 = (size_t)Bn * Dn / 4;
  const float4* x4 = (const float4*)x;
  float4* y4 = (float4*)y;
  for (size_t i = blockIdx.x * 256ull + threadIdx.x; i < n4; i += (size_t)gridDim.x * 256)
    y4[i] = x4[i];
  for (int i = blockIdx.x * 256 + threadIdx.x; i < Bn; i += gridDim.x * 256) ld[i] = 0.f;
}

// out = epilogue( (Ain + alpha*Kprev) @ w0[0:508,:] )
// mode 0: tanh(z + b0 + t*w0[509] + cond*w0[508])   (h0 of the MLP)
// mode 1: raw store                                  (u = eps @ w0[:508,:])
__global__ __launch_bounds__(256) void k_fwd0(
    const float* __restrict__ Ain, const float* __restrict__ Kprev, float alpha,
    const float* __restrict__ w0, const float* __restrict__ b0,
    const float* __restrict__ cond, float tval, float* __restrict__ out, int mode) {
  __shared__ float As[BK][TP];
  __shared__ float Bs[BK][TP];
  const int tid = threadIdx.x;
  const int ty = tid >> 4, tx = tid & 15;
  const int rowBase = blockIdx.y * BM;
  const int colBase = blockIdx.x * BN;
  const int K = Dn;  // 508
  const int lr = tid >> 2, lk = (tid & 3) * 4;   // A loader: row 0..63, k-chunk
  const int bk = tid >> 4, bc = (tid & 15) * 4;  // B loader: k-row 0..15, col-chunk
  float acc[4][4] = {};

  for (int kb = 0; kb < K; kb += BK) {
    {  // A tile (transposed store into As[k][m])
      const size_t base = (size_t)(rowBase + lr) * K;
      const int gk = kb + lk;
      float v[4];
      if (gk + 3 < K) {
        const float4 t4 = *(const float4*)(Ain + base + gk);
        v[0] = t4.x; v[1] = t4.y; v[2] = t4.z; v[3] = t4.w;
        if (Kprev) {
          const float4 k4 = *(const float4*)(Kprev + base + gk);
          v[0] += alpha * k4.x; v[1] += alpha * k4.y;
          v[2] += alpha * k4.z; v[3] += alpha * k4.w;
        }
      } else {
#pragma unroll
        for (int c = 0; c < 4; ++c) {
          const int g = gk + c;
          float vv = 0.f;
          if (g < K) {
            vv = Ain[base + g];
            if (Kprev) vv += alpha * Kprev[base + g];
          }
          v[c] = vv;
        }
      }
      As[lk + 0][lr] = v[0]; As[lk + 1][lr] = v[1];
      As[lk + 2][lr] = v[2]; As[lk + 3][lr] = v[3];
    }
    {  // B tile: w0 rows kb+bk (row-major [510][256])
      const int gk = kb + bk;
      float4 v = make_float4(0.f, 0.f, 0.f, 0.f);
      if (gk < K) v = *(const float4*)(w0 + (size_t)gk * Hn + colBase + bc);
      *(float4*)(&Bs[bk][bc]) = v;
    }
    __syncthreads();
    mm_tile(As, Bs, ty, tx, acc);
    __syncthreads();
  }

  const float* w0t = w0 + (size_t)509 * Hn;
  const float* w0c = w0 + (size_t)508 * Hn;
#pragma unroll
  for (int i = 0; i < 4; ++i) {
    const int b = rowBase + ty * 4 + i;
    const float cb = cond ? cond[b] : 0.f;
#pragma unroll
    for (int j = 0; j < 4; ++j) {
      const int n = colBase + tx * 4 + j;
      float v = acc[i][j];
      if (mode == 0) v = tanhf(v + b0[n] + tval * w0t[n] + cb * w0c[n]);
      out[(size_t)b * Hn + n] = v;
    }
  }
}

// h1 = tanh(h0 @ w1 + b1)   (K=N=256)
__global__ __launch_bounds__(256) void k_fwd1(const float* __restrict__ h0,
                                              const float* __restrict__ w1,
                                              const float* __restrict__ b1,
                                              float* __restrict__ h1out) {
  __shared__ float As[BK][TP];
  __shared__ float Bs[BK][TP];
  const int tid = threadIdx.x;
  const int ty = tid >> 4, tx = tid & 15;
  const int rowBase = blockIdx.y * BM;
  const int colBase = blockIdx.x * BN;
  const int lr = tid >> 2, lk = (tid & 3) * 4;
  const int bk = tid >> 4, bc = (tid & 15) * 4;
  float acc[4][4] = {};
  for (int kb = 0; kb < Hn; kb += BK) {
    {
      const float4 t4 = *(const float4*)(h0 + (size_t)(rowBase + lr) * Hn + kb + lk);
      As[lk + 0][lr] = t4.x; As[lk + 1][lr] = t4.y;
      As[lk + 2][lr] = t4.z; As[lk + 3][lr] = t4.w;
    }
    *(float4*)(&Bs[bk][bc]) =
        *(const float4*)(w1 + (size_t)(kb + bk) * Hn + colBase + bc);
    __syncthreads();
    mm_tile(As, Bs, ty, tx, acc);
    __syncthreads();
  }
#pragma unroll
  for (int i = 0; i < 4; ++i) {
    const int b = rowBase + ty * 4 + i;
#pragma unroll
    for (int j = 0; j < 4; ++j) {
      const int n = colBase + tx * 4 + j;
      h1out[(size_t)b * Hn + n] = tanhf(acc[i][j] + b1[n]);
    }
  }
}

// knew = h1 @ w2 + b2 ; RK4 accumulate. (K=256, N=508)
// mode 0: accb = y + coef*knew ; mode 1: accb += coef*knew ; mode 2: y = accb + coef*knew
__global__ __launch_bounds__(256) void k_fwd2(
    const float* __restrict__ h1, const float* __restrict__ w2,
    const float* __restrict__ b2, float* __restrict__ kout,
    float* __restrict__ ystate, float* __restrict__ accb, float coef, int mode) {
  __shared__ float As[BK][TP];
  __shared__ float Bs[BK][TP];
  const int tid = threadIdx.x;
  const int ty = tid >> 4, tx = tid & 15;
  const int rowBase = blockIdx.y * BM;
  const int colBase = blockIdx.x * BN;
  const int lr = tid >> 2, lk = (tid & 3) * 4;
  const int bk = tid >> 4, bc = (tid & 15) * 4;
  float acc[4][4] = {};
  for (int kb = 0; kb < Hn; kb += BK) {
    {
      const float4 t4 = *(const float4*)(h1 + (size_t)(rowBase + lr) * Hn + kb + lk);
      As[lk + 0][lr] = t4.x; As[lk + 1][lr] = t4.y;
      As[lk + 2][lr] = t4.z; As[lk + 3][lr] = t4.w;
    }
    {
      const int gc = colBase + bc;
      float4 v = make_float4(0.f, 0.f, 0.f, 0.f);
      if (gc + 3 < Dn) {
        v = *(const float4*)(w2 + (size_t)(kb + bk) * Dn + gc);
      } else {
        float tmp[4] = {0.f, 0.f, 0.f, 0.f};
#pragma unroll
        for (int c = 0; c < 4; ++c)
          if (gc + c < Dn) tmp[c] = w2[(size_t)(kb + bk) * Dn + gc + c];
        v = make_float4(tmp[0], tmp[1], tmp[2], tmp[3]);
      }
      *(float4*)(&Bs[bk][bc]) = v;
    }
    __syncthreads();
    mm_tile(As, Bs, ty, tx, acc);
    __syncthreads();
  }
#pragma unroll
  for (int i = 0; i < 4; ++i) {
    const int b = rowBase + ty * 4 + i;
#pragma unroll
    for (int j = 0; j < 4; ++j) {
      const int n = colBase + tx * 4 + j;
      if (n < Dn) {
        const float v = acc[i][j] + b2[n];
        const size_t idx = (size_t)b * Dn + n;
        kout[idx] = v;
        if (mode == 0)
          accb[idx] = ystate[idx] + coef * v;
        else if (mode == 1)
          accb[idx] += coef * v;
        else
          ystate[idx] = accb[idx] + coef * v;
      }
    }
  }
}

// g1 = g2*(1-h1^2); g1b = g1 @ w1^T; tr[b] = sum_n g1b[b,n]*(1-h0[b,n]^2)*u[b,n]
// ld[b] += scale * tr[b]
__global__ __launch_bounds__(256) void k_bwd(
    const float* __restrict__ g2, const float* __restrict__ h1,
    const float* __restrict__ w1, const float* __restrict__ h0,
    const float* __restrict__ u, float* __restrict__ ld, float scale) {
  __shared__ float As[BK][TP];
  __shared__ float Bs[BK][TP];
  __shared__ float red[BM][17];
  const int tid = threadIdx.x;
  const int ty = tid >> 4, tx = tid & 15;
  const int rowBase = blockIdx.y * BM;
  const int colBase = blockIdx.x * BN;
  const int lr = tid >> 2, lk = (tid & 3) * 4;
  const int bcol = tid >> 2, bkc = (tid & 3) * 4;  // B loader: col 0..63, k-chunk
  float acc[4][4] = {};
  for (int kb = 0; kb < Hn; kb += BK) {
    {
      const size_t base = (size_t)(rowBase + lr) * Hn + kb + lk;
      const float4 g = *(const float4*)(g2 + base);
      const float4 h = *(const float4*)(h1 + base);
      As[lk + 0][lr] = g.x * (1.f - h.x * h.x);
      As[lk + 1][lr] = g.y * (1.f - h.y * h.y);
      As[lk + 2][lr] = g.z * (1.f - h.z * h.z);
      As[lk + 3][lr] = g.w * (1.f - h.w * h.w);
    }
    {  // B[k][n] = w1[n][k]  (transposed access)
      const float4 v =
          *(const float4*)(w1 + (size_t)(colBase + bcol) * Hn + kb + bkc);
      Bs[bkc + 0][bcol] = v.x; Bs[bkc + 1][bcol] = v.y;
      Bs[bkc + 2][bcol] = v.z; Bs[bkc + 3][bcol] = v.w;
    }
    __syncthreads();
    mm_tile(As, Bs, ty, tx, acc);
    __syncthreads();
  }
#pragma unroll
  for (int i = 0; i < 4; ++i) {
    const int b = rowBase + ty * 4 + i;
    float s = 0.f;
#pragma unroll
    for (int j = 0; j < 4; ++j) {
      const int n = colBase + tx * 4 + j;
      const float h0v = h0[(size_t)b * Hn + n];
      const float uv = u[(size_t)b * Hn + n];
      s += acc[i][j] * (1.f - h0v * h0v) * uv;
    }
    red[ty * 4 + i][tx] = s;
  }
  __syncthreads();
  if (tid < BM) {
    float tot = 0.f;
#pragma unroll
    for (int x2 = 0; x2 < 16; ++x2) tot += red[tid][x2];
    atomicAdd(&ld[rowBase + tid], scale * tot);
  }
}

// g2 = eps @ w2^T   (K=508 with transposed-B access, N=256)
__global__ __launch_bounds__(256) void k_g2(const float* __restrict__ eps,
                                            const float* __restrict__ w2,
                                            float* __restrict__ g2out) {
  __shared__ float As[BK][TP];
  __shared__ float Bs[BK][TP];
  const int tid = threadIdx.x;
  const int ty = tid >> 4, tx = tid & 15;
  const int rowBase = blockIdx.y * BM;
  const int colBase = blockIdx.x * BN;
  const int K = Dn;
  const int lr = tid >> 2, lk = (tid & 3) * 4;
  const int bcol = tid >> 2, bkc = (tid & 3) * 4;
  float acc[4][4] = {};
  for (int kb = 0; kb < K; kb += BK) {
    {
      const size_t base = (size_t)(rowBase + lr) * K;
      const int gk = kb + lk;
      float v[4];
      if (gk + 3 < K) {
        const float4 t4 = *(const float4*)(eps + base + gk);
        v[0] = t4.x; v[1] = t4.y; v[2] = t4.z; v[3] = t4.w;
      } else {
#pragma unroll
        for (int c = 0; c < 4; ++c) v[c] = (gk + c < K) ? eps[base + gk + c] : 0.f;
      }
      As[lk + 0][lr] = v[0]; As[lk + 1][lr] = v[1];
      As[lk + 2][lr] = v[2]; As[lk + 3][lr] = v[3];
    }
    {  // B[k=d][n=h] = w2[h][d], w2 row-major [256][508]
      const int gk = kb + bkc;
      const size_t base = (size_t)(colBase + bcol) * Dn;
      float v[4];
      if (gk + 3 < K) {
        const float4 t4 = *(const float4*)(w2 + base + gk);
        v[0] = t4.x; v[1] = t4.y; v[2] = t4.z; v[3] = t4.w;
      } else {
#pragma unroll
        for (int c = 0; c < 4; ++c) v[c] = (gk + c < K) ? w2[base + gk + c] : 0.f;
      }
      Bs[bkc + 0][bcol] = v[0]; Bs[bkc + 1][bcol] = v[1];
      Bs[bkc + 2][bcol] = v[2]; Bs[bkc + 3][bcol] = v[3];
    }
    __syncthreads();
    mm_tile(As, Bs, ty, tx, acc);
    __syncthreads();
  }
#pragma unroll
  for (int i = 0; i < 4; ++i) {
    const int b = rowBase + ty * 4 + i;
#pragma unroll
    for (int j = 0; j < 4; ++j)
      g2out[(size_t)b * Hn + colBase + tx * 4 + j] = acc[i][j];
  }
}

__global__ __launch_bounds__(256) void k_final(const float* __restrict__ y,
                                               const float* __restrict__ ld,
                                               float* __restrict__ out) {
  const size_t n4 = (size_t)Bn * Dn / 4;
  const float4* y4 = (const float4*)y;
  float4* o4 = (float4*)out;
  for (size_t i = blockIdx.x * 256ull + threadIdx.x; i < n4; i += (size_t)gridDim.x * 256)
    o4[i] = y4[i];
  float* otail = out + (size_t)Bn * Dn;
  for (int i = blockIdx.x * 256 + threadIdx.x; i < Bn; i += gridDim.x * 256)
    otail[i] = ld[i];
}

}  // namespace

extern "C" void kernel_launch(void* const* d_in, const int* in_sizes, int n_in,
                              void* d_out, int out_size, void* d_ws, size_t ws_size,
                              hipStream_t stream) {
  const float* x = (const float*)d_in[0];
  const float* cond = (const float*)d_in[1];
  const float* eps = (const float*)d_in[2];
  const float* w0 = (const float*)d_in[3];
  const float* b0 = (const float*)d_in[4];
  const float* w1 = (const float*)d_in[5];
  const float* b1 = (const float*)d_in[6];
  const float* w2 = (const float*)d_in[7];
  const float* b2 = (const float*)d_in[8];

  float* ws = (float*)d_ws;
  const size_t BD = (size_t)Bn * Dn, BH = (size_t)Bn * Hn;
  float* y = ws;               // [B,D] ODE state
  float* kbuf = ws + BD;       // [B,D] current k_i
  float* accb = ws + 2 * BD;   // [B,D] RK4 accumulator
  float* h0 = ws + 3 * BD;     // [B,H]
  float* h1 = h0 + BH;         // [B,H]
  float* g2 = h0 + 2 * BH;     // [B,H] eps @ w2^T (constant)
  float* u = h0 + 3 * BH;      // [B,H] eps @ w0[:508] (constant)
  float* ld = h0 + 4 * BH;     // [B]

  const dim3 blk(256);
  const dim3 g256(Hn / BN, Bn / BM);               // (4,128)
  const dim3 g508((Dn + BN - 1) / BN, Bn / BM);    // (8,128)

  k_init<<<2048, blk, 0, stream>>>(x, y, ld);
  k_g2<<<g256, blk, 0, stream>>>(eps, w2, g2);
  k_fwd0<<<g256, blk, 0, stream>>>(eps, nullptr, 0.f, w0, nullptr, nullptr, 0.f, u, 1);

  const float dt = 1.f / NSTEPS;
  const float offs[4] = {0.f, 0.5f, 0.5f, 1.f};
  const float alphas[4] = {0.f, 0.5f * dt, 0.5f * dt, dt};
  const float mults[4] = {1.f, 2.f, 2.f, 1.f};

  for (int s = 0; s < NSTEPS; ++s) {
    for (int j = 0; j < 4; ++j) {
      const float t = (s + offs[j]) * dt;
      const float coef = dt / 6.f * mults[j];
      const int mode = (j == 0) ? 0 : (j == 3 ? 2 : 1);
      k_fwd0<<<g256, blk, 0, stream>>>(y, (j == 0) ? nullptr : kbuf, alphas[j],
                                       w0, b0, cond, t, h0, 0);
      k_fwd1<<<g256, blk, 0, stream>>>(h0, w1, b1, h1);
      k_fwd2<<<g508, blk, 0, stream>>>(h1, w2, b2, kbuf, y, accb, coef, mode);
      k_bwd<<<g256, blk, 0, stream>>>(g2, h1, w1, h0, u, ld, coef);
    }
  }
  k_final<<<2048, blk, 0, stream>>>(y, ld, (float*)d_out);
}

// Round 2
// 1959.140 us; speedup vs baseline: 2.4799x; 2.4799x over previous
//
#include <hip/hip_runtime.h>
#include <math.h>

namespace {

constexpr int Bn = 8192;
constexpr int Dn = 508;
constexpr int Hn = 256;
constexpr int NSTEPS = 8;
constexpr int Kp = 512;  // D padded to 512 (zero-padded on the WEIGHT side)

typedef __attribute__((ext_vector_type(8))) short short8v;
typedef __attribute__((ext_vector_type(4))) short short4v;
typedef __attribute__((ext_vector_type(4))) float f32x4;

__device__ __forceinline__ short f2b(float f) {
  union { float f; unsigned u; } v; v.f = f;
  unsigned r = v.u + 0x7fffu + ((v.u >> 16) & 1u);
  return (short)(r >> 16);
}
__device__ __forceinline__ float b2f(short s) {
  union { unsigned u; float f; } v;
  v.u = ((unsigned)(unsigned short)s) << 16;
  return v.f;
}
__device__ __forceinline__ float ftanh(float x) {
  x = fminf(fmaxf(x, -12.f), 12.f);
  const float e = __expf(2.f * x);
  return __fdividef(e - 1.f, e + 1.f);
}

// ---------------- MFMA GEMM core: C[64x64 block] = A @ B, A bf16 row-major
// [M][lda] (k contiguous), Bt bf16 row-major [N][ldb] (k contiguous, i.e. B^T).
// Wave (row0,col0) computes rows row0..+31, cols col0..+31, acc fp32.
// A-frag: [row=lane&15][k=(lane>>4)*8+j]; B-frag: [col=lane&15][k=...].
template <int KT>
__device__ __forceinline__ void gemm_bb(const short* __restrict__ A, int lda,
                                        const short* __restrict__ Bt, int ldb,
                                        int row0, int col0, int lane,
                                        f32x4 acc[2][2]) {
  const int r = lane & 15, g = lane >> 4;
  const short* a0p = A + (size_t)(row0 + r) * lda + g * 8;
  const short* a1p = A + (size_t)(row0 + 16 + r) * lda + g * 8;
  const short* b0p = Bt + (size_t)(col0 + r) * ldb + g * 8;
  const short* b1p = Bt + (size_t)(col0 + 16 + r) * ldb + g * 8;
#pragma unroll
  for (int kt = 0; kt < KT; ++kt) {
    const short8v a0 = *(const short8v*)(a0p + kt * 32);
    const short8v a1 = *(const short8v*)(a1p + kt * 32);
    const short8v b0 = *(const short8v*)(b0p + kt * 32);
    const short8v b1 = *(const short8v*)(b1p + kt * 32);
    acc[0][0] = __builtin_amdgcn_mfma_f32_16x16x32_bf16(a0, b0, acc[0][0], 0, 0, 0);
    acc[0][1] = __builtin_amdgcn_mfma_f32_16x16x32_bf16(a0, b1, acc[0][1], 0, 0, 0);
    acc[1][0] = __builtin_amdgcn_mfma_f32_16x16x32_bf16(a1, b0, acc[1][0], 0, 0, 0);
    acc[1][1] = __builtin_amdgcn_mfma_f32_16x16x32_bf16(a1, b1, acc[1][1], 0, 0, 0);
  }
}

// f32-A variant (converts to bf16 on the fly) for the per-step y update.
template <int KT>
__device__ __forceinline__ void gemm_fb(const float* __restrict__ A, int lda,
                                        const short* __restrict__ Bt, int ldb,
                                        int row0, int col0, int lane,
                                        f32x4 acc[2][2]) {
  const int r = lane & 15, g = lane >> 4;
#pragma unroll
  for (int kt = 0; kt < KT; ++kt) {
    const int k = kt * 32 + g * 8;
    short8v a0, a1;
#pragma unroll
    for (int h = 0; h < 2; ++h) {
      const float4 fa = *(const float4*)(A + (size_t)(row0 + r) * lda + k + h * 4);
      const float4 fb = *(const float4*)(A + (size_t)(row0 + 16 + r) * lda + k + h * 4);
      a0[h * 4 + 0] = f2b(fa.x); a0[h * 4 + 1] = f2b(fa.y);
      a0[h * 4 + 2] = f2b(fa.z); a0[h * 4 + 3] = f2b(fa.w);
      a1[h * 4 + 0] = f2b(fb.x); a1[h * 4 + 1] = f2b(fb.y);
      a1[h * 4 + 2] = f2b(fb.z); a1[h * 4 + 3] = f2b(fb.w);
    }
    const short8v b0 = *(const short8v*)(Bt + (size_t)(col0 + r) * ldb + k);
    const short8v b1 = *(const short8v*)(Bt + (size_t)(col0 + 16 + r) * ldb + k);
    acc[0][0] = __builtin_amdgcn_mfma_f32_16x16x32_bf16(a0, b0, acc[0][0], 0, 0, 0);
    acc[0][1] = __builtin_amdgcn_mfma_f32_16x16x32_bf16(a0, b1, acc[0][1], 0, 0, 0);
    acc[1][0] = __builtin_amdgcn_mfma_f32_16x16x32_bf16(a1, b0, acc[1][0], 0, 0, 0);
    acc[1][1] = __builtin_amdgcn_mfma_f32_16x16x32_bf16(a1, b1, acc[1][1], 0, 0, 0);
  }
}

#define GEMM_PROLOGUE()                                     \
  const int tid = threadIdx.x, wid = tid >> 6, lane = tid & 63; \
  const int row0 = blockIdx.y * 64 + (wid >> 1) * 32;       \
  const int col0 = blockIdx.x * 64 + (wid & 1) * 32;        \
  const int rq = (lane >> 4) * 4, cc = lane & 15;           \
  const f32x4 z4 = {0.f, 0.f, 0.f, 0.f};                    \
  f32x4 acc[2][2] = {{z4, z4}, {z4, z4}};

// ---------------- setup kernels ----------------

__global__ __launch_bounds__(256) void k_init(const float* __restrict__ x,
                                              float* __restrict__ y,
                                              float* __restrict__ ld) {
  const size_t n4 = (size_t)Bn * Dn / 4;
  const float4* x4 = (const float4*)x;
  float4* y4 = (float4*)y;
  for (size_t i = blockIdx.x * 256ull + threadIdx.x; i < n4; i += (size_t)gridDim.x * 256)
    y4[i] = x4[i];
  for (int i = blockIdx.x * 256 + threadIdx.x; i < Bn; i += gridDim.x * 256) ld[i] = 0.f;
}

// dst bf16 [R][ldd] = src fp32 [R][C], cols C..ldd-1 zero
__global__ __launch_bounds__(256) void k_cast_bf(const float* __restrict__ src, int R,
                                                 int C, short* __restrict__ dst, int ldd) {
  const int total = R * ldd;
  for (int idx = blockIdx.x * 256 + threadIdx.x; idx < total; idx += gridDim.x * 256) {
    const int r = idx / ldd, c = idx - r * ldd;
    dst[idx] = (c < C) ? f2b(src[(size_t)r * C + c]) : (short)0;
  }
}

// dst bf16 [Nd][ldd]: dst[n][k] = src[k][n] (src fp32 [K][N]), pads zero
__global__ __launch_bounds__(256) void k_transpose_bf(const float* __restrict__ src, int K,
                                                      int N, short* __restrict__ dst,
                                                      int Nd, int ldd) {
  const int total = Nd * ldd;
  for (int idx = blockIdx.x * 256 + threadIdx.x; idx < total; idx += gridDim.x * 256) {
    const int n = idx / ldd, k = idx - n * ldd;
    dst[idx] = (k < K && n < N) ? f2b(src[(size_t)k * N + n]) : (short)0;
  }
}

// c0[n] = sum_d b2[d] * w0[d][n]
__global__ __launch_bounds__(256) void k_c0(const float* __restrict__ w0,
                                            const float* __restrict__ b2,
                                            float* __restrict__ c0) {
  const int n = threadIdx.x;
  float s = 0.f;
#pragma unroll 8
  for (int d = 0; d < Dn; ++d) s += b2[d] * w0[(size_t)d * Hn + n];
  c0[n] = s;
}

// w20T[n][k] = sum_d w0T[n][d] * w2b[k][d]   (= w20[k][n], K=512 padded)
__global__ __launch_bounds__(256) void k_w20t(const short* __restrict__ w0T,
                                              const short* __restrict__ w2b,
                                              short* __restrict__ w20T) {
  GEMM_PROLOGUE();
  gemm_bb<16>(w0T, Kp, w2b, Kp, row0, col0, lane, acc);
#pragma unroll
  for (int i = 0; i < 2; ++i)
#pragma unroll
    for (int j = 0; j < 2; ++j)
#pragma unroll
      for (int q = 0; q < 4; ++q)
        w20T[(size_t)(row0 + i * 16 + rq + q) * Hn + col0 + j * 16 + cc] =
            f2b(acc[i][j][q]);
}

// MODE 0: z = A@B + cond*w0c ; MODE 1: u_bf = A@B ; MODE 2: g2_bf = A@B
template <int MODE>
__global__ __launch_bounds__(256) void k_ginit(const short* __restrict__ A,
                                               const short* __restrict__ Bt,
                                               const float* __restrict__ cond,
                                               const float* __restrict__ w0c,
                                               float* __restrict__ zout,
                                               short* __restrict__ bout) {
  GEMM_PROLOGUE();
  gemm_bb<16>(A, Kp, Bt, Kp, row0, col0, lane, acc);
#pragma unroll
  for (int i = 0; i < 2; ++i)
#pragma unroll
    for (int j = 0; j < 2; ++j)
#pragma unroll
      for (int q = 0; q < 4; ++q) {
        const int row = row0 + i * 16 + rq + q;
        const int col = col0 + j * 16 + cc;
        const size_t idx = (size_t)row * Hn + col;
        if (MODE == 0)
          zout[idx] = acc[i][j][q] + cond[row] * w0c[col];
        else
          bout[idx] = f2b(acc[i][j][q]);
      }
}

// ---------------- per-eval kernels ----------------

// h0 = tanh(z + alpha*kz + b0 + t*w0t); m0 = (1-h0^2)*u
__global__ __launch_bounds__(256) void k_h0(const float* __restrict__ z,
                                            const float* __restrict__ kz, float alpha,
                                            const float* __restrict__ b0,
                                            const float* __restrict__ w0t, float tval,
                                            const short* __restrict__ u,
                                            short* __restrict__ h0,
                                            short* __restrict__ m0) {
  const int i4 = blockIdx.x * 256 + threadIdx.x;
  const int base = i4 * 4;
  const int c = base & (Hn - 1);
  const float4 zv = *(const float4*)(z + base);
  float4 kv = make_float4(0.f, 0.f, 0.f, 0.f);
  if (alpha != 0.f) kv = *(const float4*)(kz + base);
  const float4 b0v = *(const float4*)(b0 + c);
  const float4 wtv = *(const float4*)(w0t + c);
  const short4v uv = *(const short4v*)(u + base);
  float a[4] = {zv.x + alpha * kv.x + b0v.x + tval * wtv.x,
                zv.y + alpha * kv.y + b0v.y + tval * wtv.y,
                zv.z + alpha * kv.z + b0v.z + tval * wtv.z,
                zv.w + alpha * kv.w + b0v.w + tval * wtv.w};
  short4v hv, mv;
#pragma unroll
  for (int e = 0; e < 4; ++e) {
    const float h = ftanh(a[e]);
    hv[e] = f2b(h);
    mv[e] = f2b((1.f - h * h) * b2f(uv[e]));
  }
  *(short4v*)(h0 + base) = hv;
  *(short4v*)(m0 + base) = mv;
}

// h1 = tanh(h0@w1 + b1); g1 = g2*(1-h1^2); hsum (+)= mult*h1
__global__ __launch_bounds__(256) void k_fwd1(const short* __restrict__ h0,
                                              const short* __restrict__ w1T,
                                              const float* __restrict__ b1,
                                              const short* __restrict__ g2,
                                              short* __restrict__ h1,
                                              short* __restrict__ g1,
                                              float* __restrict__ hsum, float mult,
                                              int first) {
  GEMM_PROLOGUE();
  gemm_bb<8>(h0, Hn, w1T, Hn, row0, col0, lane, acc);
#pragma unroll
  for (int i = 0; i < 2; ++i)
#pragma unroll
    for (int j = 0; j < 2; ++j) {
      const int col = col0 + j * 16 + cc;
      const float b1c = b1[col];
#pragma unroll
      for (int q = 0; q < 4; ++q) {
        const int row = row0 + i * 16 + rq + q;
        const size_t idx = (size_t)row * Hn + col;
        const float v = ftanh(acc[i][j][q] + b1c);
        h1[idx] = f2b(v);
        g1[idx] = f2b(b2f(g2[idx]) * (1.f - v * v));
        hsum[idx] = first ? (mult * v) : (hsum[idx] + mult * v);
      }
    }
}

// kz = h1@w20 + c0 (modes: 0 first: kz=v,kzacc=v; 1 mid: kz=v,kzacc+=mult*v;
//                   2 last: z += dt6*(kzacc+v))
__global__ __launch_bounds__(256) void k_kz(const short* __restrict__ h1,
                                            const short* __restrict__ w20T,
                                            const float* __restrict__ c0,
                                            float* __restrict__ kz,
                                            float* __restrict__ kzacc,
                                            float* __restrict__ z, float mult, int mode,
                                            float dt6) {
  GEMM_PROLOGUE();
  gemm_bb<8>(h1, Hn, w20T, Hn, row0, col0, lane, acc);
#pragma unroll
  for (int i = 0; i < 2; ++i)
#pragma unroll
    for (int j = 0; j < 2; ++j) {
      const int col = col0 + j * 16 + cc;
      const float c0c = c0[col];
#pragma unroll
      for (int q = 0; q < 4; ++q) {
        const int row = row0 + i * 16 + rq + q;
        const size_t idx = (size_t)row * Hn + col;
        const float v = acc[i][j][q] + c0c;
        if (mode == 0) {
          kz[idx] = v; kzacc[idx] = v;
        } else if (mode == 1) {
          kz[idx] = v; kzacc[idx] += mult * v;
        } else {
          z[idx] += dt6 * (kzacc[idx] + v);
        }
      }
    }
}

// tr partials: C = g1@w1^T; ld[row] += scale * sum_col C*m0
__global__ __launch_bounds__(256) void k_bwd(const short* __restrict__ g1,
                                             const short* __restrict__ w1b,
                                             const short* __restrict__ m0,
                                             float* __restrict__ ld, float scale) {
  GEMM_PROLOGUE();
  gemm_bb<8>(g1, Hn, w1b, Hn, row0, col0, lane, acc);
#pragma unroll
  for (int i = 0; i < 2; ++i)
#pragma unroll
    for (int q = 0; q < 4; ++q) {
      const int row = row0 + i * 16 + rq + q;
      float s = 0.f;
#pragma unroll
      for (int j = 0; j < 2; ++j) {
        const int col = col0 + j * 16 + cc;
        s += acc[i][j][q] * b2f(m0[(size_t)row * Hn + col]);
      }
      s += __shfl_xor(s, 1);
      s += __shfl_xor(s, 2);
      s += __shfl_xor(s, 4);
      s += __shfl_xor(s, 8);
      if (cc == 0) atomicAdd(&ld[row], scale * s);
    }
}

// y += dt6 * hsum@w2 + dt*b2   (N=508 guarded, Bt rows padded to 512)
__global__ __launch_bounds__(256) void k_yupd(const float* __restrict__ hsum,
                                              const short* __restrict__ w2T,
                                              const float* __restrict__ b2,
                                              float* __restrict__ y, float dt6,
                                              float dt) {
  GEMM_PROLOGUE();
  gemm_fb<8>(hsum, Hn, w2T, Hn, row0, col0, lane, acc);
#pragma unroll
  for (int i = 0; i < 2; ++i)
#pragma unroll
    for (int j = 0; j < 2; ++j) {
      const int col = col0 + j * 16 + cc;
      if (col < Dn) {
        const float b2c = b2[col];
#pragma unroll
        for (int q = 0; q < 4; ++q) {
          const int row = row0 + i * 16 + rq + q;
          y[(size_t)row * Dn + col] += dt6 * acc[i][j][q] + dt * b2c;
        }
      }
    }
}

__global__ __launch_bounds__(256) void k_final(const float* __restrict__ y,
                                               const float* __restrict__ ld,
                                               float* __restrict__ out) {
  const size_t n4 = (size_t)Bn * Dn / 4;
  const float4* y4 = (const float4*)y;
  float4* o4 = (float4*)out;
  for (size_t i = blockIdx.x * 256ull + threadIdx.x; i < n4; i += (size_t)gridDim.x * 256)
    o4[i] = y4[i];
  float* otail = out + (size_t)Bn * Dn;
  for (int i = blockIdx.x * 256 + threadIdx.x; i < Bn; i += gridDim.x * 256)
    otail[i] = ld[i];
}

}  // namespace

extern "C" void kernel_launch(void* const* d_in, const int* in_sizes, int n_in,
                              void* d_out, int out_size, void* d_ws, size_t ws_size,
                              hipStream_t stream) {
  const float* x = (const float*)d_in[0];
  const float* cond = (const float*)d_in[1];
  const float* eps = (const float*)d_in[2];
  const float* w0 = (const float*)d_in[3];
  const float* b0 = (const float*)d_in[4];
  const float* w1 = (const float*)d_in[5];
  const float* b1 = (const float*)d_in[6];
  const float* w2 = (const float*)d_in[7];
  const float* b2 = (const float*)d_in[8];
  const float* w0c = w0 + (size_t)508 * Hn;  // cond row
  const float* w0t = w0 + (size_t)509 * Hn;  // time row

  const size_t BD = (size_t)Bn * Dn, BH = (size_t)Bn * Hn, BKp = (size_t)Bn * Kp;
  char* p = (char*)d_ws;
  auto alloc_f = [&](size_t n) { float* r = (float*)p; p += n * 4; return r; };
  auto alloc_s = [&](size_t n) { short* r = (short*)p; p += ((n * 2 + 15) & ~15ull); return r; };

  float* y = alloc_f(BD);
  float* z = alloc_f(BH);
  float* kz = alloc_f(BH);
  float* kzacc = alloc_f(BH);
  float* hsum = alloc_f(BH);
  float* ld = alloc_f(Bn);
  float* c0 = alloc_f(256);
  short* xp = alloc_s(BKp);
  short* epsp = alloc_s(BKp);
  short* h0 = alloc_s(BH);
  short* h1 = alloc_s(BH);
  short* g1 = alloc_s(BH);
  short* g2 = alloc_s(BH);
  short* u = alloc_s(BH);
  short* m0 = alloc_s(BH);
  short* w0T = alloc_s(256 * 512);
  short* w1T = alloc_s(256 * 256);
  short* w1b = alloc_s(256 * 256);
  short* w2b = alloc_s(256 * 512);
  short* w2T = alloc_s(512 * 256);
  short* w20T = alloc_s(256 * 256);

  const dim3 blk(256);
  const dim3 gH(Hn / 64, Bn / 64);   // (4,128)
  const dim3 gD(Kp / 64, Bn / 64);   // (8,128)
  const dim3 gW(4, 4);

  // ---- setup ----
  k_init<<<2048, blk, 0, stream>>>(x, y, ld);
  k_cast_bf<<<4096, blk, 0, stream>>>(x, Bn, Dn, xp, Kp);
  k_cast_bf<<<4096, blk, 0, stream>>>(eps, Bn, Dn, epsp, Kp);
  k_cast_bf<<<256, blk, 0, stream>>>(w1, Hn, Hn, w1b, Hn);
  k_cast_bf<<<512, blk, 0, stream>>>(w2, Hn, Dn, w2b, Kp);
  k_transpose_bf<<<256, blk, 0, stream>>>(w1, Hn, Hn, w1T, Hn, Hn);
  k_transpose_bf<<<512, blk, 0, stream>>>(w0, Dn, Hn, w0T, Hn, Kp);
  k_transpose_bf<<<512, blk, 0, stream>>>(w2, Hn, Dn, w2T, Kp, Hn);
  k_c0<<<1, blk, 0, stream>>>(w0, b2, c0);
  k_w20t<<<gW, blk, 0, stream>>>(w0T, w2b, w20T);
  k_ginit<0><<<gH, blk, 0, stream>>>(xp, w0T, cond, w0c, z, nullptr);
  k_ginit<1><<<gH, blk, 0, stream>>>(epsp, w0T, nullptr, nullptr, nullptr, u);
  k_ginit<2><<<gH, blk, 0, stream>>>(epsp, w2b, nullptr, nullptr, nullptr, g2);

  const float dt = 1.f / NSTEPS;
  const float dt6 = dt / 6.f;
  const float offs[4] = {0.f, 0.5f, 0.5f, 1.f};
  const float alphas[4] = {0.f, 0.5f * dt, 0.5f * dt, dt};
  const float mults[4] = {1.f, 2.f, 2.f, 1.f};

  for (int s = 0; s < NSTEPS; ++s) {
    for (int j = 0; j < 4; ++j) {
      const float t = (s + offs[j]) * dt;
      k_h0<<<2048, blk, 0, stream>>>(z, kz, alphas[j], b0, w0t, t, u, h0, m0);
      k_fwd1<<<gH, blk, 0, stream>>>(h0, w1T, b1, g2, h1, g1, hsum, mults[j],
                                     j == 0 ? 1 : 0);
      const int kzmode = (j == 0) ? 0 : (j == 3 ? 2 : 1);
      k_kz<<<gH, blk, 0, stream>>>(h1, w20T, c0, kz, kzacc, z, mults[j], kzmode, dt6);
      k_bwd<<<gH, blk, 0, stream>>>(g1, w1b, m0, ld, dt6 * mults[j]);
    }
    k_yupd<<<gD, blk, 0, stream>>>(hsum, w2T, b2, y, dt6, dt);
  }
  k_final<<<2048, blk, 0, stream>>>(y, ld, (float*)d_out);
}

// Round 3
// 1823.567 us; speedup vs baseline: 2.6643x; 1.0743x over previous
//
#include <hip/hip_runtime.h>
#include <math.h>

namespace {

constexpr int Bn = 8192;
constexpr int Dn = 508;
constexpr int Hn = 256;
constexpr int NSTEPS = 8;
constexpr int Kp = 512;  // D padded to 512 (zero-padded on the WEIGHT side)
constexpr float DT = 1.f / NSTEPS;
constexpr float DT6 = DT / 6.f;

typedef __attribute__((ext_vector_type(8))) short short8v;
typedef __attribute__((ext_vector_type(4))) float f32x4;

__device__ __forceinline__ short f2b(float f) {
  union { float f; unsigned u; } v; v.f = f;
  unsigned r = v.u + 0x7fffu + ((v.u >> 16) & 1u);
  return (short)(r >> 16);
}
__device__ __forceinline__ float b2f(short s) {
  union { unsigned u; float f; } v;
  v.u = ((unsigned)(unsigned short)s) << 16;
  return v.f;
}
__device__ __forceinline__ float ftanh(float x) {
  x = fminf(fmaxf(x, -12.f), 12.f);
  const float e = __expf(2.f * x);
  return __fdividef(e - 1.f, e + 1.f);
}

// ---------------- shared 64x64-block MFMA core for SETUP kernels (validated r2)
template <int KT>
__device__ __forceinline__ void gemm_bb(const short* __restrict__ A, int lda,
                                        const short* __restrict__ Bt, int ldb,
                                        int row0, int col0, int lane,
                                        f32x4 acc[2][2]) {
  const int r = lane & 15, g = lane >> 4;
  const short* a0p = A + (size_t)(row0 + r) * lda + g * 8;
  const short* a1p = A + (size_t)(row0 + 16 + r) * lda + g * 8;
  const short* b0p = Bt + (size_t)(col0 + r) * ldb + g * 8;
  const short* b1p = Bt + (size_t)(col0 + 16 + r) * ldb + g * 8;
#pragma unroll
  for (int kt = 0; kt < KT; ++kt) {
    const short8v a0 = *(const short8v*)(a0p + kt * 32);
    const short8v a1 = *(const short8v*)(a1p + kt * 32);
    const short8v b0 = *(const short8v*)(b0p + kt * 32);
    const short8v b1 = *(const short8v*)(b1p + kt * 32);
    acc[0][0] = __builtin_amdgcn_mfma_f32_16x16x32_bf16(a0, b0, acc[0][0], 0, 0, 0);
    acc[0][1] = __builtin_amdgcn_mfma_f32_16x16x32_bf16(a0, b1, acc[0][1], 0, 0, 0);
    acc[1][0] = __builtin_amdgcn_mfma_f32_16x16x32_bf16(a1, b0, acc[1][0], 0, 0, 0);
    acc[1][1] = __builtin_amdgcn_mfma_f32_16x16x32_bf16(a1, b1, acc[1][1], 0, 0, 0);
  }
}

#define GEMM_PROLOGUE()                                     \
  const int tid = threadIdx.x, wid = tid >> 6, lane = tid & 63; \
  const int row0 = blockIdx.y * 64 + (wid >> 1) * 32;       \
  const int col0 = blockIdx.x * 64 + (wid & 1) * 32;        \
  const int rq = (lane >> 4) * 4, cc = lane & 15;           \
  const f32x4 z4 = {0.f, 0.f, 0.f, 0.f};                    \
  f32x4 acc[2][2] = {{z4, z4}, {z4, z4}};

// ---------------- setup kernels (unchanged from round 2) ----------------

__global__ __launch_bounds__(256) void k_cast_bf(const float* __restrict__ src, int R,
                                                 int C, short* __restrict__ dst, int ldd) {
  const int total = R * ldd;
  for (int idx = blockIdx.x * 256 + threadIdx.x; idx < total; idx += gridDim.x * 256) {
    const int r = idx / ldd, c = idx - r * ldd;
    dst[idx] = (c < C) ? f2b(src[(size_t)r * C + c]) : (short)0;
  }
}

__global__ __launch_bounds__(256) void k_transpose_bf(const float* __restrict__ src, int K,
                                                      int N, short* __restrict__ dst,
                                                      int Nd, int ldd) {
  const int total = Nd * ldd;
  for (int idx = blockIdx.x * 256 + threadIdx.x; idx < total; idx += gridDim.x * 256) {
    const int n = idx / ldd, k = idx - n * ldd;
    dst[idx] = (k < K && n < N) ? f2b(src[(size_t)k * N + n]) : (short)0;
  }
}

__global__ __launch_bounds__(256) void k_c0(const float* __restrict__ w0,
                                            const float* __restrict__ b2,
                                            float* __restrict__ c0) {
  const int n = threadIdx.x;
  float s = 0.f;
#pragma unroll 8
  for (int d = 0; d < Dn; ++d) s += b2[d] * w0[(size_t)d * Hn + n];
  c0[n] = s;
}

__global__ __launch_bounds__(256) void k_w20t(const short* __restrict__ w0T,
                                              const short* __restrict__ w2b,
                                              short* __restrict__ w20T) {
  GEMM_PROLOGUE();
  gemm_bb<16>(w0T, Kp, w2b, Kp, row0, col0, lane, acc);
#pragma unroll
  for (int i = 0; i < 2; ++i)
#pragma unroll
    for (int j = 0; j < 2; ++j)
#pragma unroll
      for (int q = 0; q < 4; ++q)
        w20T[(size_t)(row0 + i * 16 + rq + q) * Hn + col0 + j * 16 + cc] =
            f2b(acc[i][j][q]);
}

// MODE 0: z = A@B + cond*w0c (f32) ; MODE 1/2: bout = bf16(A@B)
template <int MODE>
__global__ __launch_bounds__(256) void k_ginit(const short* __restrict__ A,
                                               const short* __restrict__ Bt,
                                               const float* __restrict__ cond,
                                               const float* __restrict__ w0c,
                                               float* __restrict__ zout,
                                               short* __restrict__ bout) {
  GEMM_PROLOGUE();
  gemm_bb<16>(A, Kp, Bt, Kp, row0, col0, lane, acc);
#pragma unroll
  for (int i = 0; i < 2; ++i)
#pragma unroll
    for (int j = 0; j < 2; ++j)
#pragma unroll
      for (int q = 0; q < 4; ++q) {
        const int row = row0 + i * 16 + rq + q;
        const int col = col0 + j * 16 + cc;
        const size_t idx = (size_t)row * Hn + col;
        if (MODE == 0)
          zout[idx] = acc[i][j][q] + cond[row] * w0c[col];
        else
          bout[idx] = f2b(acc[i][j][q]);
      }
}

// ---------------- the fused ODE kernel ----------------

// swizzled short-index into a [16][256] bf16 LDS tile (bank-conflict-free
// column-slice b128 reads: byte ^= ((row&7)<<4)  =>  short idx ^= ((row&7)<<3))
__device__ __forceinline__ int swz(int row, int col) {
  return (row * 256 + col) ^ ((row & 7) << 3);
}

// C[16 x 16*NT] += LDS_A[16][256] @ B ; A swizzled-LDS, Bt row-major [*][256]
// (Bt[n][k] layout, i.e. B^T with k contiguous). Wave covers cols
// [colbase, colbase+16*NT).
template <int NT>
__device__ __forceinline__ void gemm_a_lds(const short* __restrict__ As,
                                           const short* __restrict__ Bt,
                                           int colbase, int cc, int g,
                                           f32x4* acc) {
  const int arow = cc;          // A-frag row = lane&15
  const int kb0 = g * 8;        // A/B-frag k-base = (lane>>4)*8
#pragma unroll
  for (int ks = 0; ks < 8; ++ks) {
    const int k = kb0 + ks * 32;
    const short8v a = *(const short8v*)(As + ((arow * 256 + k) ^ ((arow & 7) << 3)));
#pragma unroll
    for (int nt = 0; nt < NT; ++nt) {
      const short8v b = *(const short8v*)(Bt + (size_t)(colbase + nt * 16 + cc) * 256 + k);
      acc[nt] = __builtin_amdgcn_mfma_f32_16x16x32_bf16(a, b, acc[nt], 0, 0, 0);
    }
  }
}

__global__ __launch_bounds__(256, 2) void k_mega(
    const float* __restrict__ zg, const short* __restrict__ u_g,
    const short* __restrict__ g2_g, const short* __restrict__ w1T,
    const short* __restrict__ w1b, const short* __restrict__ w20T,
    const short* __restrict__ w2T, const float* __restrict__ b0,
    const float* __restrict__ w0t, const float* __restrict__ b1,
    const float* __restrict__ c0, const float* __restrict__ b2,
    const float* __restrict__ x, float* __restrict__ yout,
    float* __restrict__ ldout) {
  __shared__ short h0s[16 * 256];
  __shared__ short h1s[16 * 256];
  __shared__ short g1s[16 * 256];
  __shared__ float red[16][4];

  const int tid = threadIdx.x;
  const int w = tid >> 6, lane = tid & 63;
  const int cc = lane & 15, g = lane >> 4, rq = g * 4;
  const int r0 = blockIdx.x * 16;
  const int cb = w * 64;  // wave's 64-col strip for the H-space GEMMs

  // per-lane column constants
  float b0c[4], w0tc[4], b1c[4], c0c[4];
#pragma unroll
  for (int nt = 0; nt < 4; ++nt) {
    const int col = cb + nt * 16 + cc;
    b0c[nt] = b0[col];
    w0tc[nt] = w0t[col];
    b1c[nt] = b1[col];
    c0c[nt] = c0[col];
  }

  // per-lane register state in C-fragment layout: (row=r0+rq+q, col=cb+nt*16+cc)
  float z_[4][4], kza[4][4], kzp[4][4], u_[4][4], g2_[4][4], m0_[4][4], hs[4][4];
  float tr_[4] = {0.f, 0.f, 0.f, 0.f};
#pragma unroll
  for (int nt = 0; nt < 4; ++nt)
#pragma unroll
    for (int q = 0; q < 4; ++q) {
      const size_t idx = (size_t)(r0 + rq + q) * Hn + cb + nt * 16 + cc;
      z_[nt][q] = zg[idx];
      u_[nt][q] = b2f(u_g[idx]);
      g2_[nt][q] = b2f(g2_g[idx]);
      kzp[nt][q] = 0.f;
    }

  constexpr float offs[4] = {0.f, 0.5f, 0.5f, 1.f};
  constexpr float alph[4] = {0.f, 0.5f * DT, 0.5f * DT, DT};
  constexpr float mlt[4] = {1.f, 2.f, 2.f, 1.f};
  const f32x4 zero4 = {0.f, 0.f, 0.f, 0.f};

  for (int s = 0; s < NSTEPS; ++s) {
#pragma unroll
    for (int j = 0; j < 4; ++j) {
      const float tval = ((float)s + offs[j]) * DT;
      // ---- A: h0 = tanh(z + a*kz_prev + b0 + t*w0t); m0 = (1-h0^2)*u
#pragma unroll
      for (int nt = 0; nt < 4; ++nt)
#pragma unroll
        for (int q = 0; q < 4; ++q) {
          const float pre =
              z_[nt][q] + alph[j] * kzp[nt][q] + b0c[nt] + tval * w0tc[nt];
          const float h = ftanh(pre);
          m0_[nt][q] = (1.f - h * h) * u_[nt][q];
          h0s[swz(rq + q, cb + nt * 16 + cc)] = f2b(h);
        }
      __syncthreads();
      // ---- B: h1 = tanh(h0@w1 + b1); g1 = g2*(1-h1^2); hs accumulate
      {
        f32x4 acc[4] = {zero4, zero4, zero4, zero4};
        gemm_a_lds<4>(h0s, w1T, cb, cc, g, acc);
#pragma unroll
        for (int nt = 0; nt < 4; ++nt)
#pragma unroll
          for (int q = 0; q < 4; ++q) {
            const float v = ftanh(acc[nt][q] + b1c[nt]);
            const int si = swz(rq + q, cb + nt * 16 + cc);
            h1s[si] = f2b(v);
            g1s[si] = f2b(g2_[nt][q] * (1.f - v * v));
            hs[nt][q] = (s == 0 && j == 0) ? v : hs[nt][q] + mlt[j] * v;
          }
      }
      __syncthreads();
      // ---- C: kz = h1@w20 + c0 ; RK4 state update
      {
        f32x4 acc[4] = {zero4, zero4, zero4, zero4};
        gemm_a_lds<4>(h1s, w20T, cb, cc, g, acc);
#pragma unroll
        for (int nt = 0; nt < 4; ++nt)
#pragma unroll
          for (int q = 0; q < 4; ++q) {
            const float kzv = acc[nt][q] + c0c[nt];
            if (j == 0)
              kza[nt][q] = kzv;
            else
              kza[nt][q] += mlt[j] * kzv;
            if (j < 3)
              kzp[nt][q] = kzv;
            else
              z_[nt][q] += DT6 * kza[nt][q];
          }
      }
      // ---- D: trace: (g1@w1^T) . m0, row-reduced
      {
        f32x4 acc[4] = {zero4, zero4, zero4, zero4};
        gemm_a_lds<4>(g1s, w1b, cb, cc, g, acc);
#pragma unroll
        for (int q = 0; q < 4; ++q) {
          float sq = 0.f;
#pragma unroll
          for (int nt = 0; nt < 4; ++nt) sq += acc[nt][q] * m0_[nt][q];
          tr_[q] += (DT6 * mlt[j]) * sq;
        }
      }
      __syncthreads();
    }
  }

  // ---- final: y = x + DT6 * HS@w2 + b2  (sum of dt*b2 over 8 steps = b2)
#pragma unroll
  for (int nt = 0; nt < 4; ++nt)
#pragma unroll
    for (int q = 0; q < 4; ++q)
      h0s[swz(rq + q, cb + nt * 16 + cc)] = f2b(hs[nt][q]);
  __syncthreads();
  {
    f32x4 acc[8] = {zero4, zero4, zero4, zero4, zero4, zero4, zero4, zero4};
    gemm_a_lds<8>(h0s, w2T, w * 128, cc, g, acc);
#pragma unroll
    for (int nt = 0; nt < 8; ++nt)
#pragma unroll
      for (int q = 0; q < 4; ++q) {
        const int col = w * 128 + nt * 16 + cc;
        if (col < Dn) {
          const size_t ix = (size_t)(r0 + rq + q) * Dn + col;
          yout[ix] = x[ix] + DT6 * acc[nt][q] + b2[col];
        }
      }
  }

  // ---- trace reduction: sum over cc lanes, then over waves
#pragma unroll
  for (int q = 0; q < 4; ++q) {
    float v = tr_[q];
    v += __shfl_xor(v, 1);
    v += __shfl_xor(v, 2);
    v += __shfl_xor(v, 4);
    v += __shfl_xor(v, 8);
    if (cc == 0) red[rq + q][w] = v;
  }
  __syncthreads();
  if (tid < 16)
    ldout[r0 + tid] = red[tid][0] + red[tid][1] + red[tid][2] + red[tid][3];
}

}  // namespace

extern "C" void kernel_launch(void* const* d_in, const int* in_sizes, int n_in,
                              void* d_out, int out_size, void* d_ws, size_t ws_size,
                              hipStream_t stream) {
  const float* x = (const float*)d_in[0];
  const float* cond = (const float*)d_in[1];
  const float* eps = (const float*)d_in[2];
  const float* w0 = (const float*)d_in[3];
  const float* b0 = (const float*)d_in[4];
  const float* w1 = (const float*)d_in[5];
  const float* b1 = (const float*)d_in[6];
  const float* w2 = (const float*)d_in[7];
  const float* b2 = (const float*)d_in[8];
  const float* w0c = w0 + (size_t)508 * Hn;  // cond row
  const float* w0t = w0 + (size_t)509 * Hn;  // time row

  const size_t BD = (size_t)Bn * Dn, BH = (size_t)Bn * Hn, BKp = (size_t)Bn * Kp;
  char* p = (char*)d_ws;
  auto alloc_f = [&](size_t n) { float* r = (float*)p; p += n * 4; return r; };
  auto alloc_s = [&](size_t n) { short* r = (short*)p; p += ((n * 2 + 15) & ~15ull); return r; };

  float* zg = alloc_f(BH);
  float* c0 = alloc_f(256);
  short* xp = alloc_s(BKp);
  short* epsp = alloc_s(BKp);
  short* u_g = alloc_s(BH);
  short* g2_g = alloc_s(BH);
  short* w0T = alloc_s(256 * 512);
  short* w1T = alloc_s(256 * 256);
  short* w1b = alloc_s(256 * 256);
  short* w2b = alloc_s(256 * 512);
  short* w2T = alloc_s(512 * 256);
  short* w20T = alloc_s(256 * 256);

  float* yout = (float*)d_out;          // [B, D]
  float* ldout = (float*)d_out + BD;    // [B]

  const dim3 blk(256);
  const dim3 gH(Hn / 64, Bn / 64);  // (4,128)
  const dim3 gW(4, 4);

  // ---- setup (weights + z/u/g2 precompute) ----
  k_cast_bf<<<4096, blk, 0, stream>>>(x, Bn, Dn, xp, Kp);
  k_cast_bf<<<4096, blk, 0, stream>>>(eps, Bn, Dn, epsp, Kp);
  k_cast_bf<<<256, blk, 0, stream>>>(w1, Hn, Hn, w1b, Hn);
  k_cast_bf<<<512, blk, 0, stream>>>(w2, Hn, Dn, w2b, Kp);
  k_transpose_bf<<<256, blk, 0, stream>>>(w1, Hn, Hn, w1T, Hn, Hn);
  k_transpose_bf<<<512, blk, 0, stream>>>(w0, Dn, Hn, w0T, Hn, Kp);
  k_transpose_bf<<<512, blk, 0, stream>>>(w2, Hn, Dn, w2T, Kp, Hn);
  k_c0<<<1, blk, 0, stream>>>(w0, b2, c0);
  k_w20t<<<gW, blk, 0, stream>>>(w0T, w2b, w20T);
  k_ginit<0><<<gH, blk, 0, stream>>>(xp, w0T, cond, w0c, zg, nullptr);
  k_ginit<1><<<gH, blk, 0, stream>>>(epsp, w0T, nullptr, nullptr, nullptr, u_g);
  k_ginit<2><<<gH, blk, 0, stream>>>(epsp, w2b, nullptr, nullptr, nullptr, g2_g);

  // ---- the whole ODE in one kernel ----
  k_mega<<<dim3(Bn / 16), blk, 0, stream>>>(zg, u_g, g2_g, w1T, w1b, w20T, w2T,
                                            b0, w0t, b1, c0, b2, x, yout, ldout);
}

// Round 4
// 1131.263 us; speedup vs baseline: 4.2947x; 1.6120x over previous
//
#include <hip/hip_runtime.h>
#include <math.h>

namespace {

constexpr int Bn = 8192;
constexpr int Dn = 508;
constexpr int Hn = 256;
constexpr int NSTEPS = 8;
constexpr int Kp = 512;  // D padded to 512 (zero-padded on the WEIGHT side)
constexpr float DT = 1.f / NSTEPS;
constexpr float DT6 = DT / 6.f;

typedef __attribute__((ext_vector_type(8))) short short8v;
typedef __attribute__((ext_vector_type(4))) float f32x4;

__device__ __forceinline__ short f2b(float f) {
  union { float f; unsigned u; } v; v.f = f;
  unsigned r = v.u + 0x7fffu + ((v.u >> 16) & 1u);
  return (short)(r >> 16);
}
__device__ __forceinline__ float b2f(short s) {
  union { unsigned u; float f; } v;
  v.u = ((unsigned)(unsigned short)s) << 16;
  return v.f;
}
__device__ __forceinline__ unsigned pk2(short lo, short hi) {
  return ((unsigned)(unsigned short)lo) | (((unsigned)(unsigned short)hi) << 16);
}
__device__ __forceinline__ float upk_lo(unsigned p) {
  union { unsigned u; float f; } v; v.u = p << 16; return v.f;
}
__device__ __forceinline__ float upk_hi(unsigned p) {
  union { unsigned u; float f; } v; v.u = p & 0xffff0000u; return v.f;
}
__device__ __forceinline__ float ftanh(float x) {
  x = fminf(fmaxf(x, -12.f), 12.f);
  const float e = __expf(2.f * x);
  return __fdividef(e - 1.f, e + 1.f);
}

// ---------------- shared 64x64-block MFMA core for SETUP kernels (validated r2)
template <int KT>
__device__ __forceinline__ void gemm_bb(const short* __restrict__ A, int lda,
                                        const short* __restrict__ Bt, int ldb,
                                        int row0, int col0, int lane,
                                        f32x4 acc[2][2]) {
  const int r = lane & 15, g = lane >> 4;
  const short* a0p = A + (size_t)(row0 + r) * lda + g * 8;
  const short* a1p = A + (size_t)(row0 + 16 + r) * lda + g * 8;
  const short* b0p = Bt + (size_t)(col0 + r) * ldb + g * 8;
  const short* b1p = Bt + (size_t)(col0 + 16 + r) * ldb + g * 8;
#pragma unroll
  for (int kt = 0; kt < KT; ++kt) {
    const short8v a0 = *(const short8v*)(a0p + kt * 32);
    const short8v a1 = *(const short8v*)(a1p + kt * 32);
    const short8v b0 = *(const short8v*)(b0p + kt * 32);
    const short8v b1 = *(const short8v*)(b1p + kt * 32);
    acc[0][0] = __builtin_amdgcn_mfma_f32_16x16x32_bf16(a0, b0, acc[0][0], 0, 0, 0);
    acc[0][1] = __builtin_amdgcn_mfma_f32_16x16x32_bf16(a0, b1, acc[0][1], 0, 0, 0);
    acc[1][0] = __builtin_amdgcn_mfma_f32_16x16x32_bf16(a1, b0, acc[1][0], 0, 0, 0);
    acc[1][1] = __builtin_amdgcn_mfma_f32_16x16x32_bf16(a1, b1, acc[1][1], 0, 0, 0);
  }
}

#define GEMM_PROLOGUE()                                     \
  const int tid = threadIdx.x, wid = tid >> 6, lane = tid & 63; \
  const int row0 = blockIdx.y * 64 + (wid >> 1) * 32;       \
  const int col0 = blockIdx.x * 64 + (wid & 1) * 32;        \
  const int rq = (lane >> 4) * 4, cc = lane & 15;           \
  const f32x4 z4 = {0.f, 0.f, 0.f, 0.f};                    \
  f32x4 acc[2][2] = {{z4, z4}, {z4, z4}};

// ---------------- setup kernels (unchanged, validated) ----------------

__global__ __launch_bounds__(256) void k_cast_bf(const float* __restrict__ src, int R,
                                                 int C, short* __restrict__ dst, int ldd) {
  const int total = R * ldd;
  for (int idx = blockIdx.x * 256 + threadIdx.x; idx < total; idx += gridDim.x * 256) {
    const int r = idx / ldd, c = idx - r * ldd;
    dst[idx] = (c < C) ? f2b(src[(size_t)r * C + c]) : (short)0;
  }
}

__global__ __launch_bounds__(256) void k_transpose_bf(const float* __restrict__ src, int K,
                                                      int N, short* __restrict__ dst,
                                                      int Nd, int ldd) {
  const int total = Nd * ldd;
  for (int idx = blockIdx.x * 256 + threadIdx.x; idx < total; idx += gridDim.x * 256) {
    const int n = idx / ldd, k = idx - n * ldd;
    dst[idx] = (k < K && n < N) ? f2b(src[(size_t)k * N + n]) : (short)0;
  }
}

__global__ __launch_bounds__(256) void k_c0(const float* __restrict__ w0,
                                            const float* __restrict__ b2,
                                            float* __restrict__ c0) {
  const int n = threadIdx.x;
  float s = 0.f;
#pragma unroll 8
  for (int d = 0; d < Dn; ++d) s += b2[d] * w0[(size_t)d * Hn + n];
  c0[n] = s;
}

__global__ __launch_bounds__(256) void k_w20t(const short* __restrict__ w0T,
                                              const short* __restrict__ w2b,
                                              short* __restrict__ w20T) {
  GEMM_PROLOGUE();
  gemm_bb<16>(w0T, Kp, w2b, Kp, row0, col0, lane, acc);
#pragma unroll
  for (int i = 0; i < 2; ++i)
#pragma unroll
    for (int j = 0; j < 2; ++j)
#pragma unroll
      for (int q = 0; q < 4; ++q)
        w20T[(size_t)(row0 + i * 16 + rq + q) * Hn + col0 + j * 16 + cc] =
            f2b(acc[i][j][q]);
}

// MODE 0: z = A@B + cond*w0c (f32) ; MODE 1/2: bout = bf16(A@B)
template <int MODE>
__global__ __launch_bounds__(256) void k_ginit(const short* __restrict__ A,
                                               const short* __restrict__ Bt,
                                               const float* __restrict__ cond,
                                               const float* __restrict__ w0c,
                                               float* __restrict__ zout,
                                               short* __restrict__ bout) {
  GEMM_PROLOGUE();
  gemm_bb<16>(A, Kp, Bt, Kp, row0, col0, lane, acc);
#pragma unroll
  for (int i = 0; i < 2; ++i)
#pragma unroll
    for (int j = 0; j < 2; ++j)
#pragma unroll
      for (int q = 0; q < 4; ++q) {
        const int row = row0 + i * 16 + rq + q;
        const int col = col0 + j * 16 + cc;
        const size_t idx = (size_t)row * Hn + col;
        if (MODE == 0)
          zout[idx] = acc[i][j][q] + cond[row] * w0c[col];
        else
          bout[idx] = f2b(acc[i][j][q]);
      }
}

// ---------------- the fused ODE kernel ----------------
// Block: 512 threads = 8 waves; 32 batch rows per block; wave w owns the
// 32-col strip [w*32, w*32+32) of the 256-dim h-space. State lives in
// registers in MFMA C-fragment layout: (row = rb*16 + (lane>>4)*4 + q,
// col = w*32 + nt*16 + (lane&15)), rb,nt in {0,1}, q in 0..3.

// swizzled short-index into a [32][256] bf16 LDS tile:
// byte ^= ((row&7)<<4)  =>  short idx ^= ((row&7)<<3). Keeps 8-short align.
__device__ __forceinline__ int swz(int row, int col) {
  return (row * 256 + col) ^ ((row & 7) << 3);
}

// acc[rb][nt] += A(32x256, swizzled LDS) @ Bt-strip. Bt row-major [N][256]
// (k contiguous, B^T). Wave covers cols [cb, cb+16*NT).
template <int NT>
__device__ __forceinline__ void gemm2(const short* __restrict__ As,
                                      const short* __restrict__ Bt, int cb,
                                      int cc, int g, f32x4 acc[][NT]) {
  const int kb0 = g * 8;
#pragma unroll
  for (int ks = 0; ks < 8; ++ks) {
    const int k = kb0 + ks * 32;
    const short8v a0 = *(const short8v*)(As + swz(cc, k));
    const short8v a1 = *(const short8v*)(As + swz(cc + 16, k));
#pragma unroll
    for (int nt = 0; nt < NT; ++nt) {
      const short8v b = *(const short8v*)(Bt + (size_t)(cb + nt * 16 + cc) * 256 + k);
      acc[0][nt] = __builtin_amdgcn_mfma_f32_16x16x32_bf16(a0, b, acc[0][nt], 0, 0, 0);
      acc[1][nt] = __builtin_amdgcn_mfma_f32_16x16x32_bf16(a1, b, acc[1][nt], 0, 0, 0);
    }
  }
}

__global__ __launch_bounds__(512, 2) void k_mega(
    const float* __restrict__ zg, const short* __restrict__ u_g,
    const short* __restrict__ g2_g, const short* __restrict__ w1T,
    const short* __restrict__ w1b, const short* __restrict__ w20T,
    const short* __restrict__ w2T, const float* __restrict__ b0,
    const float* __restrict__ w0t, const float* __restrict__ b1,
    const float* __restrict__ c0, const float* __restrict__ b2,
    const float* __restrict__ x, float* __restrict__ yout,
    float* __restrict__ ldout) {
  __shared__ short h0s[32 * 256];
  __shared__ short h1s[32 * 256];
  __shared__ short g1s[32 * 256];
  __shared__ float red[32][8];

  const int tid = threadIdx.x;
  const int w = tid >> 6, lane = tid & 63;
  const int cc = lane & 15, g = lane >> 4, rq = g * 4;
  const int r0 = blockIdx.x * 32;
  const int cb = w * 32;  // wave's 32-col strip for the H-space GEMMs

  // per-lane column constants (f32)
  float b0c[2], w0tc[2], b1c[2], c0c[2];
#pragma unroll
  for (int nt = 0; nt < 2; ++nt) {
    const int col = cb + nt * 16 + cc;
    b0c[nt] = b0[col];
    w0tc[nt] = w0t[col];
    b1c[nt] = b1[col];
    c0c[nt] = c0[col];
  }

  // persistent per-thread state
  float z_[2][2][4], kza[2][2][4], kzp[2][2][4], hs[2][2][4], m0_[2][2][4];
  unsigned u_pk[2][2][2], g2_pk[2][2][2];  // bf16 pairs packed along q
  float tr_[2][4];
#pragma unroll
  for (int rb = 0; rb < 2; ++rb)
#pragma unroll
    for (int nt = 0; nt < 2; ++nt) {
      const size_t i0 = (size_t)(r0 + rb * 16 + rq) * Hn + cb + nt * 16 + cc;
#pragma unroll
      for (int q = 0; q < 4; ++q) {
        z_[rb][nt][q] = zg[i0 + (size_t)q * Hn];
        kzp[rb][nt][q] = 0.f;
        hs[rb][nt][q] = 0.f;
      }
      u_pk[rb][nt][0] = pk2(u_g[i0], u_g[i0 + Hn]);
      u_pk[rb][nt][1] = pk2(u_g[i0 + 2 * Hn], u_g[i0 + 3 * Hn]);
      g2_pk[rb][nt][0] = pk2(g2_g[i0], g2_g[i0 + Hn]);
      g2_pk[rb][nt][1] = pk2(g2_g[i0 + 2 * Hn], g2_g[i0 + 3 * Hn]);
    }
#pragma unroll
  for (int rb = 0; rb < 2; ++rb)
#pragma unroll
    for (int q = 0; q < 4; ++q) tr_[rb][q] = 0.f;

  constexpr float offs[4] = {0.f, 0.5f, 0.5f, 1.f};
  constexpr float alph[4] = {0.f, 0.5f * DT, 0.5f * DT, DT};
  constexpr float mlt[4] = {1.f, 2.f, 2.f, 1.f};
  const f32x4 zero4 = {0.f, 0.f, 0.f, 0.f};

  for (int s = 0; s < NSTEPS; ++s) {
#pragma unroll
    for (int j = 0; j < 4; ++j) {
      const float tval = ((float)s + offs[j]) * DT;
      // ---- A: h0 = tanh(z + a*kzp + b0 + t*w0t); m0 = (1-h0^2)*u
#pragma unroll
      for (int rb = 0; rb < 2; ++rb)
#pragma unroll
        for (int nt = 0; nt < 2; ++nt)
#pragma unroll
          for (int q = 0; q < 4; ++q) {
            const float pre =
                z_[rb][nt][q] + alph[j] * kzp[rb][nt][q] + b0c[nt] + tval * w0tc[nt];
            const float h = ftanh(pre);
            const float uq = (q & 1) ? upk_hi(u_pk[rb][nt][q >> 1])
                                     : upk_lo(u_pk[rb][nt][q >> 1]);
            m0_[rb][nt][q] = (1.f - h * h) * uq;
            h0s[swz(rb * 16 + rq + q, cb + nt * 16 + cc)] = f2b(h);
          }
      __syncthreads();
      // ---- B: h1 = tanh(h0@w1 + b1); g1 = g2*(1-h1^2); hs += mlt*h1
      {
        f32x4 acc[2][2] = {{zero4, zero4}, {zero4, zero4}};
        gemm2<2>(h0s, w1T, cb, cc, g, acc);
#pragma unroll
        for (int rb = 0; rb < 2; ++rb)
#pragma unroll
          for (int nt = 0; nt < 2; ++nt)
#pragma unroll
            for (int q = 0; q < 4; ++q) {
              const float v = ftanh(acc[rb][nt][q] + b1c[nt]);
              const float g2q = (q & 1) ? upk_hi(g2_pk[rb][nt][q >> 1])
                                        : upk_lo(g2_pk[rb][nt][q >> 1]);
              const int si = swz(rb * 16 + rq + q, cb + nt * 16 + cc);
              h1s[si] = f2b(v);
              g1s[si] = f2b(g2q * (1.f - v * v));
              hs[rb][nt][q] += mlt[j] * v;
            }
      }
      __syncthreads();
      // ---- C: kz = h1@w20 + c0 ; RK4 z-state update
      {
        f32x4 acc[2][2] = {{zero4, zero4}, {zero4, zero4}};
        gemm2<2>(h1s, w20T, cb, cc, g, acc);
#pragma unroll
        for (int rb = 0; rb < 2; ++rb)
#pragma unroll
          for (int nt = 0; nt < 2; ++nt)
#pragma unroll
            for (int q = 0; q < 4; ++q) {
              const float kzv = acc[rb][nt][q] + c0c[nt];
              if (j == 0)
                kza[rb][nt][q] = kzv;
              else
                kza[rb][nt][q] += mlt[j] * kzv;
              if (j < 3)
                kzp[rb][nt][q] = kzv;
              else
                z_[rb][nt][q] += DT6 * kza[rb][nt][q];
            }
      }
      // ---- D: trace: (g1@w1^T) . m0, accumulated per row
      {
        f32x4 acc[2][2] = {{zero4, zero4}, {zero4, zero4}};
        gemm2<2>(g1s, w1b, cb, cc, g, acc);
#pragma unroll
        for (int rb = 0; rb < 2; ++rb)
#pragma unroll
          for (int q = 0; q < 4; ++q) {
            float sq = acc[rb][0][q] * m0_[rb][0][q] + acc[rb][1][q] * m0_[rb][1][q];
            tr_[rb][q] += (DT6 * mlt[j]) * sq;
          }
      }
      __syncthreads();
    }
  }

  // ---- final: y = x + DT6 * HS@w2 + b2  (sum of dt*b2 over 8 steps = b2)
#pragma unroll
  for (int rb = 0; rb < 2; ++rb)
#pragma unroll
    for (int nt = 0; nt < 2; ++nt)
#pragma unroll
      for (int q = 0; q < 4; ++q)
        h0s[swz(rb * 16 + rq + q, cb + nt * 16 + cc)] = f2b(hs[rb][nt][q]);
  __syncthreads();
  {
    f32x4 facc[2][4] = {{zero4, zero4, zero4, zero4}, {zero4, zero4, zero4, zero4}};
    gemm2<4>(h0s, w2T, w * 64, cc, g, facc);
#pragma unroll
    for (int rb = 0; rb < 2; ++rb)
#pragma unroll
      for (int nt = 0; nt < 4; ++nt) {
        const int col = w * 64 + nt * 16 + cc;
        if (col < Dn) {
          const float b2c = b2[col];
#pragma unroll
          for (int q = 0; q < 4; ++q) {
            const size_t ix = (size_t)(r0 + rb * 16 + rq + q) * Dn + col;
            yout[ix] = x[ix] + DT6 * facc[rb][nt][q] + b2c;
          }
        }
      }
  }

  // ---- trace reduction: over the 16 cc-lanes, then over 8 waves
#pragma unroll
  for (int rb = 0; rb < 2; ++rb)
#pragma unroll
    for (int q = 0; q < 4; ++q) {
      float v = tr_[rb][q];
      v += __shfl_xor(v, 1);
      v += __shfl_xor(v, 2);
      v += __shfl_xor(v, 4);
      v += __shfl_xor(v, 8);
      if (cc == 0) red[rb * 16 + rq + q][w] = v;
    }
  __syncthreads();
  if (tid < 32) {
    float t = 0.f;
#pragma unroll
    for (int ww = 0; ww < 8; ++ww) t += red[tid][ww];
    ldout[r0 + tid] = t;
  }
}

}  // namespace

extern "C" void kernel_launch(void* const* d_in, const int* in_sizes, int n_in,
                              void* d_out, int out_size, void* d_ws, size_t ws_size,
                              hipStream_t stream) {
  const float* x = (const float*)d_in[0];
  const float* cond = (const float*)d_in[1];
  const float* eps = (const float*)d_in[2];
  const float* w0 = (const float*)d_in[3];
  const float* b0 = (const float*)d_in[4];
  const float* w1 = (const float*)d_in[5];
  const float* b1 = (const float*)d_in[6];
  const float* w2 = (const float*)d_in[7];
  const float* b2 = (const float*)d_in[8];
  const float* w0c = w0 + (size_t)508 * Hn;  // cond row
  const float* w0t = w0 + (size_t)509 * Hn;  // time row

  const size_t BD = (size_t)Bn * Dn, BH = (size_t)Bn * Hn, BKp = (size_t)Bn * Kp;
  char* p = (char*)d_ws;
  auto alloc_f = [&](size_t n) { float* r = (float*)p; p += n * 4; return r; };
  auto alloc_s = [&](size_t n) { short* r = (short*)p; p += ((n * 2 + 15) & ~15ull); return r; };

  float* zg = alloc_f(BH);
  float* c0 = alloc_f(256);
  short* xp = alloc_s(BKp);
  short* epsp = alloc_s(BKp);
  short* u_g = alloc_s(BH);
  short* g2_g = alloc_s(BH);
  short* w0T = alloc_s(256 * 512);
  short* w1T = alloc_s(256 * 256);
  short* w1b = alloc_s(256 * 256);
  short* w2b = alloc_s(256 * 512);
  short* w2T = alloc_s(512 * 256);
  short* w20T = alloc_s(256 * 256);

  float* yout = (float*)d_out;        // [B, D]
  float* ldout = (float*)d_out + BD;  // [B]

  const dim3 blk(256);
  const dim3 gH(Hn / 64, Bn / 64);  // (4,128)
  const dim3 gW(4, 4);

  // ---- setup (weights + z/u/g2 precompute) ----
  k_cast_bf<<<4096, blk, 0, stream>>>(x, Bn, Dn, xp, Kp);
  k_cast_bf<<<4096, blk, 0, stream>>>(eps, Bn, Dn, epsp, Kp);
  k_cast_bf<<<256, blk, 0, stream>>>(w1, Hn, Hn, w1b, Hn);
  k_cast_bf<<<512, blk, 0, stream>>>(w2, Hn, Dn, w2b, Kp);
  k_transpose_bf<<<256, blk, 0, stream>>>(w1, Hn, Hn, w1T, Hn, Hn);
  k_transpose_bf<<<512, blk, 0, stream>>>(w0, Dn, Hn, w0T, Hn, Kp);
  k_transpose_bf<<<512, blk, 0, stream>>>(w2, Hn, Dn, w2T, Kp, Hn);
  k_c0<<<1, blk, 0, stream>>>(w0, b2, c0);
  k_w20t<<<gW, blk, 0, stream>>>(w0T, w2b, w20T);
  k_ginit<0><<<gH, blk, 0, stream>>>(xp, w0T, cond, w0c, zg, nullptr);
  k_ginit<1><<<gH, blk, 0, stream>>>(epsp, w0T, nullptr, nullptr, nullptr, u_g);
  k_ginit<2><<<gH, blk, 0, stream>>>(epsp, w2b, nullptr, nullptr, nullptr, g2_g);

  // ---- the whole ODE in one kernel ----
  k_mega<<<dim3(Bn / 32), dim3(512), 0, stream>>>(zg, u_g, g2_g, w1T, w1b, w20T,
                                                  w2T, b0, w0t, b1, c0, b2, x,
                                                  yout, ldout);
}